// Round 1
// baseline (428.065 us; speedup 1.0000x reference)
//
#include <hip/hip_runtime.h>

// 2D Haar DWT: x (16,64,256,256) f32 -> out (16,256,128,128) f32.
// Pure bandwidth kernel: 256 MiB in + 256 MiB out; roofline ~81 us @ 6.3 TB/s.
//
// Each thread: one float4 per input row-pair (2 complete 2x2 blocks),
// emits float2 per subband plane. All loads/stores fully coalesced.

__global__ __launch_bounds__(256) void dwt_haar_kernel(
    const float* __restrict__ x, float* __restrict__ out) {
    const int n = blockIdx.x * blockDim.x + threadIdx.x;
    // n in [0, 1024 * 128 * 64)
    const int j2  = n & 63;        // which float4 chunk along input width (256 floats = 64 chunks)
    const int rst = n >> 6;
    const int i   = rst & 127;     // output row
    const int bc  = rst >> 7;      // b*C + c, 0..1023

    const float* plane = x + (size_t)bc * (256 * 256);
    const float4 v0 = *((const float4*)(plane + (2 * i)     * 256) + j2); // a0 b0 a1 b1
    const float4 v1 = *((const float4*)(plane + (2 * i + 1) * 256) + j2); // c0 d0 c1 d1

    const float a0 = v0.x, b0 = v0.y, a1 = v0.z, b1 = v0.w;
    const float c0 = v1.x, d0 = v1.y, c1 = v1.z, d1 = v1.w;

    const float2 cA = { (a0 + b0 + c0 + d0) * 0.5f, (a1 + b1 + c1 + d1) * 0.5f };
    const float2 cH = { (c0 + d0 - a0 - b0) * 0.5f, (c1 + d1 - a1 - b1) * 0.5f };
    const float2 cV = { (b0 + d0 - a0 - c0) * 0.5f, (b1 + d1 - a1 - c1) * 0.5f };
    const float2 cD = { (a0 - b0 - c0 + d0) * 0.5f, (a1 - b1 - c1 + d1) * 0.5f };

    // out flat (floats): ((bc*4 + k)*128 + i)*128 + j ; in float2 units:
    // (bc*4 + k)*8192 + i*64 + j2 ; subband plane stride = 8192 float2.
    float2* o = (float2*)out + (size_t)bc * 4 * 8192 + (size_t)i * 64 + j2;
    o[0]         = cA;
    o[8192]      = cH;
    o[2 * 8192]  = cV;
    o[3 * 8192]  = cD;
}

extern "C" void kernel_launch(void* const* d_in, const int* in_sizes, int n_in,
                              void* d_out, int out_size, void* d_ws, size_t ws_size,
                              hipStream_t stream) {
    const float* x = (const float*)d_in[0];
    float* out = (float*)d_out;
    // total threads = 1024 planes * 128 rows * 64 chunks = 8388608
    const int total = 1024 * 128 * 64;
    dwt_haar_kernel<<<total / 256, 256, 0, stream>>>(x, out);
}